// Round 9
// baseline (813.918 us; speedup 1.0000x reference)
//
#include <hip/hip_runtime.h>
#include <hip/hip_fp16.h>

#define TSTEPS 512   // LSTM sequence length (2048/4)
#define HID    64

typedef _Float16 h8 __attribute__((ext_vector_type(8)));

__device__ __forceinline__ float sigm(float x) {
  return 1.0f / (1.0f + __expf(-x));
}
__device__ __forceinline__ float tanh_(float x) {
  return 1.0f - 2.0f / (1.0f + __expf(2.0f * x));
}

// ---------------------------------------------------------------------------
// Kernel 1: conv1 (3->16, k=3, same) + maxpool2.  x:[256,2048,3] -> t1:[256,1024,16]
// ---------------------------------------------------------------------------
__global__ __launch_bounds__(256) void conv1_pool(
    const float* __restrict__ x, const float* __restrict__ w,
    const float* __restrict__ bias, float* __restrict__ out) {
  __shared__ float ws[144];
  __shared__ float bs[16];
  const int tid = threadIdx.x;
  if (tid < 144) ws[tid] = w[tid];
  if (tid < 16)  bs[tid] = bias[tid];
  __syncthreads();

  const int idx = blockIdx.x * 256 + tid;   // b*1024 + t2
  const int b  = idx >> 10;
  const int t2 = idx & 1023;
  const float* xb = x + (size_t)b * 2048 * 3;
  const int p0 = 2 * t2;

  float xv[4][3];
#pragma unroll
  for (int j = 0; j < 4; ++j) {
    const int p = p0 - 1 + j;
    const bool ok = (p >= 0) && (p < 2048);
#pragma unroll
    for (int c = 0; c < 3; ++c) xv[j][c] = ok ? xb[p * 3 + c] : 0.0f;
  }

  float4 o4[4];
  float* op = (float*)o4;
#pragma unroll
  for (int o = 0; o < 16; ++o) {
    float s0 = bs[o], s1 = bs[o];
#pragma unroll
    for (int c = 0; c < 3; ++c) {
#pragma unroll
      for (int k = 0; k < 3; ++k) {
        const float wv = ws[(o * 3 + c) * 3 + k];
        s0 = fmaf(xv[k][c],     wv, s0);
        s1 = fmaf(xv[k + 1][c], wv, s1);
      }
    }
    op[o] = fmaxf(s0, s1);
  }
  float4* dst = (float4*)(out + (size_t)idx * 16);
  dst[0] = o4[0]; dst[1] = o4[1]; dst[2] = o4[2]; dst[3] = o4[3];
}

// ---------------------------------------------------------------------------
// Kernel 2: conv2 (16->32, k=3, same) + maxpool2. t1:[256,1024,16] -> feat:[256,512,32]
// ---------------------------------------------------------------------------
__global__ __launch_bounds__(256) void conv2_pool(
    const float* __restrict__ t1, const float* __restrict__ w,
    const float* __restrict__ bias, float* __restrict__ out) {
  __shared__ float ws[1536];
  __shared__ float bs[32];
  const int tid = threadIdx.x;
  for (int i = tid; i < 1536; i += 256) ws[i] = w[i];
  if (tid < 32) bs[tid] = bias[tid];
  __syncthreads();

  const int idx = blockIdx.x * 256 + tid;   // b*512 + t2
  const int b  = idx >> 9;
  const int t2 = idx & 511;
  const float* tb = t1 + (size_t)b * 1024 * 16;
  const int p0 = 2 * t2;

  float4 r4[4][4];
  float* r = (float*)r4;
#pragma unroll
  for (int j = 0; j < 4; ++j) {
    const int p = p0 - 1 + j;
    if (p >= 0 && p < 1024) {
      const float4* s = (const float4*)(tb + p * 16);
      r4[j][0] = s[0]; r4[j][1] = s[1]; r4[j][2] = s[2]; r4[j][3] = s[3];
    } else {
      const float4 z = {0.f, 0.f, 0.f, 0.f};
      r4[j][0] = z; r4[j][1] = z; r4[j][2] = z; r4[j][3] = z;
    }
  }

  float4 o4[8];
  float* op = (float*)o4;
#pragma unroll 4
  for (int o = 0; o < 32; ++o) {
    float s0 = bs[o], s1 = bs[o];
    const float* wo = &ws[o * 48];
#pragma unroll
    for (int c = 0; c < 16; ++c) {
      const float w0 = wo[c * 3], w1 = wo[c * 3 + 1], w2 = wo[c * 3 + 2];
      s0 = fmaf(r[0 * 16 + c], w0, s0);
      s0 = fmaf(r[1 * 16 + c], w1, s0);
      s0 = fmaf(r[2 * 16 + c], w2, s0);
      s1 = fmaf(r[1 * 16 + c], w0, s1);
      s1 = fmaf(r[2 * 16 + c], w1, s1);
      s1 = fmaf(r[3 * 16 + c], w2, s1);
    }
    op[o] = fmaxf(s0, s1);
  }
  float4* dst = (float4*)(out + (size_t)idx * 32);
#pragma unroll
  for (int q = 0; q < 8; ++q) dst[q] = o4[q];
}

// ---------------------------------------------------------------------------
// Kernel 2.5: pack LSTM weights to fp16, unified half-row layout.
//   Wh[row][0..63], row in [0,1024):  half = row>>9, r = row&511
//     half0: acts = h0.  r<256 -> w_hh0 row r;  r>=256 -> w_ih1 row r-256
//     half1: r<256 -> [w_ih0 row r (32) | zeros(32)] (acts = x_t padded)
//            r>=256 -> w_hh1 row r-256 (acts = h1)
//   biasv[r] = b_ih + b_hh of row r (added by half0 thread only)
// ---------------------------------------------------------------------------
__global__ __launch_bounds__(64) void pack_weights(
    const float* __restrict__ w_ih0, const float* __restrict__ w_hh0,
    const float* __restrict__ b_ih0, const float* __restrict__ b_hh0,
    const float* __restrict__ w_ih1, const float* __restrict__ w_hh1,
    const float* __restrict__ b_ih1, const float* __restrict__ b_hh1,
    __half* __restrict__ Wh, float* __restrict__ biasv) {
  const int row  = blockIdx.x;   // 0..1023
  const int j    = threadIdx.x;  // 0..63
  const int half = row >> 9;
  const int r    = row & 511;
  float v;
  if (half == 0) {
    v = (r < 256) ? w_hh0[r * 64 + j] : w_ih1[(r - 256) * 64 + j];
    if (j == 0)
      biasv[r] = (r < 256) ? (b_ih0[r] + b_hh0[r])
                           : (b_ih1[r - 256] + b_hh1[r - 256]);
  } else {
    v = (r < 256) ? ((j < 32) ? w_ih0[r * 32 + j] : 0.0f)
                  : w_hh1[(r - 256) * 64 + j];
  }
  Wh[row * 64 + j] = (__half)v;
}

// ---------------------------------------------------------------------------
// Kernel 3: fused 2-layer LSTM + fc.  One block per batch element, 16 waves
// (1024 threads).  Thread = (half, row): half = tid>>9, r = tid&511.
//
// Weight residency by construction: 64 fp16 weights = 32 VGPRs; total
// pressure ~55 < 64, so even at the compiler's 8-waves/EU occupancy target
// the weights fit in registers — rematerializing them gains nothing (the
// round-2..8 failure mode is priced out, not fought).
//
// Acts via v_readlane, not LDS broadcast: each wave's 64-element act vector
// lives one-element-per-lane in its OWN registers (h0 maintained redundantly
// by all half0 waves; h1 by waves 12-15; x_t loaded 1 b32/lane by waves
// 8-11).  readlane -> SGPR -> v_fma_mix_f32 (fp32 acc, fp16 weight operand).
// One barrier per step; pre[] double-buffered on t&1.
// ---------------------------------------------------------------------------
#define RL(bits, i) __uint_as_float((unsigned)__builtin_amdgcn_readlane((int)(bits), (i)))

__global__ __launch_bounds__(1024, 4) void lstm_fused(
    const float* __restrict__ feat,
    const __half* __restrict__ Wh, const float* __restrict__ biasv,
    const float* __restrict__ fc_w, const float* __restrict__ fc_b,
    float* __restrict__ out) {
  __shared__ float featL[128 * 32];   // 16 KB: 128 steps of x (32 floats each)
  __shared__ float pre[2][2][512];    // [half][t&1][row], 8 KB
  __shared__ float hfin[64];          // final h1 for the fc epilogue

  const int tid  = threadIdx.x;
  const int wv   = tid >> 6;          // wave 0..15
  const int u    = tid & 63;          // lane
  const int r    = tid & 511;         // gate-row
  const int half = tid >> 9;
  const int b    = blockIdx.x;

  // ---- fp16 weight half-row -> 32 VGPRs (8 x 16B vector loads) ----
  h8 w[8];
  {
    const h8* ws8 = (const h8*)(Wh + (size_t)tid * 64);
#pragma unroll
    for (int k = 0; k < 8; ++k) w[k] = ws8[k];
  }
  const float bias = (half == 0) ? biasv[r] : 0.0f;

  const bool isH0 = (wv < 8);                  // acts = own h0, does L0 update
  const bool isX  = (wv >= 8) && (wv < 12);    // acts = x_t (lanes 32+ zero)
  const bool isH1 = (wv >= 12);                // acts = own h1, does L1 update

  float h0 = 0.f, c0 = 0.f, h1 = 0.f, c1 = 0.f;
  const float* fgb = feat + (size_t)b * TSTEPS * 32;

  for (int t = 0; t <= TSTEPS; ++t) {
    // stage 128 steps of x (1024 float4, one per thread)
    if ((t & 127) == 0 && t < TSTEPS) {
      if (t) __syncthreads();          // all waves past previous chunk reads
      ((float4*)featL)[tid] = ((const float4*)(fgb + t * 32))[tid];
      __syncthreads();                 // staged data visible
    }

    // ---------- act selection (wave-uniform roles) ----------
    float actv;
    if (isH0)      actv = h0;
    else if (isX)  actv = (u < 32 && t < TSTEPS) ? featL[(t & 127) * 32 + u] : 0.0f;
    else           actv = h1;
    const unsigned abits = __float_as_uint(actv);

    // ---------- gate phase: 64 MACs, acts via readlane ----------
    float a0 = bias, a1 = 0.f, a2 = 0.f, a3 = 0.f;
#pragma unroll
    for (int k = 0; k < 8; ++k) {
      const h8 wk = w[k];
      a0 = fmaf((float)wk[0], RL(abits, 8 * k + 0), a0);
      a1 = fmaf((float)wk[1], RL(abits, 8 * k + 1), a1);
      a2 = fmaf((float)wk[2], RL(abits, 8 * k + 2), a2);
      a3 = fmaf((float)wk[3], RL(abits, 8 * k + 3), a3);
      a0 = fmaf((float)wk[4], RL(abits, 8 * k + 4), a0);
      a1 = fmaf((float)wk[5], RL(abits, 8 * k + 5), a1);
      a2 = fmaf((float)wk[6], RL(abits, 8 * k + 6), a2);
      a3 = fmaf((float)wk[7], RL(abits, 8 * k + 7), a3);
    }
    pre[half][t & 1][r] = (a0 + a1) + (a2 + a3);
    // boundary-t values are garbage but never consumed

    __syncthreads();   // the ONE barrier per step

    // ---------- update phase ----------
    const int tb = t & 1;
    if (isH0 && t < TSTEPS) {          // layer0 update (private h0/c0 per wave)
      const float pi = pre[0][tb][u]       + pre[1][tb][u];
      const float pf = pre[0][tb][64 + u]  + pre[1][tb][64 + u];
      const float pg = pre[0][tb][128 + u] + pre[1][tb][128 + u];
      const float po = pre[0][tb][192 + u] + pre[1][tb][192 + u];
      const float i = sigm(pi), f = sigm(pf), g = tanh_(pg), o = sigm(po);
      c0 = fmaf(f, c0, i * g);
      h0 = o * tanh_(c0);
    }
    if (isH1 && t >= 1) {              // layer1 update (time t-1, private h1/c1)
      const float pi = pre[0][tb][256 + u] + pre[1][tb][256 + u];
      const float pf = pre[0][tb][320 + u] + pre[1][tb][320 + u];
      const float pg = pre[0][tb][384 + u] + pre[1][tb][384 + u];
      const float po = pre[0][tb][448 + u] + pre[1][tb][448 + u];
      const float i = sigm(pi), f = sigm(pf), g = tanh_(pg), o = sigm(po);
      c1 = fmaf(f, c1, i * g);
      h1 = o * tanh_(c1);
    }
  }

  // fc epilogue: wave 12 holds h1[T-1] one-per-lane; stage via LDS (same-wave
  // write->read is ordered, no barrier needed)
  if (wv == 12) {
    hfin[u] = h1;
    if (u < 5) {
      float s = fc_b[u];
      const float* wr = fc_w + u * HID;
#pragma unroll
      for (int k = 0; k < HID; ++k) s = fmaf(wr[k], hfin[k], s);
      out[b * 5 + u] = s;
    }
  }
}

// ---------------------------------------------------------------------------
extern "C" void kernel_launch(void* const* d_in, const int* in_sizes, int n_in,
                              void* d_out, int out_size, void* d_ws, size_t ws_size,
                              hipStream_t stream) {
  (void)in_sizes; (void)n_in; (void)out_size; (void)ws_size;
  const float* x    = (const float*)d_in[0];
  const float* c1w  = (const float*)d_in[1];
  const float* c1b  = (const float*)d_in[2];
  const float* c2w  = (const float*)d_in[3];
  const float* c2b  = (const float*)d_in[4];
  const float* wih0 = (const float*)d_in[5];
  const float* whh0 = (const float*)d_in[6];
  const float* bih0 = (const float*)d_in[7];
  const float* bhh0 = (const float*)d_in[8];
  const float* wih1 = (const float*)d_in[9];
  const float* whh1 = (const float*)d_in[10];
  const float* bih1 = (const float*)d_in[11];
  const float* bhh1 = (const float*)d_in[12];
  const float* fcw  = (const float*)d_in[13];
  const float* fcb  = (const float*)d_in[14];
  float* out = (float*)d_out;

  float* t1   = (float*)d_ws;                       // [256,1024,16] = 16 MB
  float* feat = t1 + (size_t)256 * 1024 * 16;       // [256,512,32]  = 16 MB
  // Wh/biasv reuse the t1 region (dead after conv2_pool; stream-ordered)
  __half* Wh   = (__half*)t1;                       // [1024][64] fp16 = 128 KB
  float* biasv = t1 + 65536;                        // [512] floats (256 KB offset)

  conv1_pool<<<1024, 256, 0, stream>>>(x, c1w, c1b, t1);
  conv2_pool<<<512, 256, 0, stream>>>(t1, c2w, c2b, feat);
  pack_weights<<<1024, 64, 0, stream>>>(wih0, whh0, bih0, bhh0,
                                        wih1, whh1, bih1, bhh1, Wh, biasv);
  lstm_fused<<<256, 1024, 0, stream>>>(feat, Wh, biasv, fcw, fcb, out);
}